// Round 12
// baseline (171.871 us; speedup 1.0000x reference)
//
#include <hip/hip_runtime.h>
#include <hip/hip_bf16.h>
#include <math.h>

// ---------------- problem constants ----------------
constexpr int Bn = 2, Hn = 12, BHn = 24;
constexpr int Nn = 2048, Dn = 64;
constexpr int Mn = 266, MPn = 272;          // M padded to 272 (zero-filled)
constexpr int E3n = 192, DHn = 128, Tn = 128;
constexpr int Cn = 128, NCn = 16;           // chunking

#define DNRM 0.35355339059327373f   // 64^-0.25
#define KEPS 1e-3f
#define DEPS 1e-6f
#define LNEPS 1e-5f

// ---------------- ws layout (bytes) ----------------
static const size_t OFF_QF   = 0;            // bf16 [BH][N][MP]   26,738,688
static const size_t OFF_KF   = 26738688;     // bf16 [BH][N][MP]   (live until k_attn)
static const size_t OFF_QK   = 53477376;     // FREE region (qk now lives in LDS)
static const size_t OFF_KPRE = 66256896;     // f32  [BH][NC][MP]     417,792
static const size_t OFF_S    = 66674688;     // bf16 [BH][NC][192][272] (S^T) 40,108,032
static const size_t OFF_WT   = OFF_QK;       // bf16 ewt+dwt -> DEAD qk region (fix r11 alias bug)
static const size_t WS_NEED  = 106782720;

// ---------------- helpers ----------------
using bf16x8 = __attribute__((ext_vector_type(8))) short;
using f32x4  = __attribute__((ext_vector_type(4))) float;

__device__ inline float u2f(unsigned int u) {
  union { float f; unsigned int i; } c; c.i = u << 16; return c.f;
}
__device__ inline unsigned short f2u(float x) {
  __hip_bfloat16 h = __float2bfloat16(x);
  unsigned short u; __builtin_memcpy(&u, &h, 2); return u;
}
__device__ inline void unpack8(uint4 v, float* a) {
  a[0] = u2f(v.x & 0xffffu); a[1] = u2f(v.x >> 16);
  a[2] = u2f(v.y & 0xffffu); a[3] = u2f(v.y >> 16);
  a[4] = u2f(v.z & 0xffffu); a[5] = u2f(v.z >> 16);
  a[6] = u2f(v.w & 0xffffu); a[7] = u2f(v.w >> 16);
}
__device__ inline ushort4 f4tobf(float4 v) {
  ushort4 o;
  o.x = f2u(v.x); o.y = f2u(v.y); o.z = f2u(v.z); o.w = f2u(v.w);
  return o;
}

// ================= K1: MFMA performer features ==================
__global__ __launch_bounds__(256) void k_features_mfma(
    const float* __restrict__ q, const float* __restrict__ k,
    const float* __restrict__ proj,
    unsigned short* __restrict__ qf, unsigned short* __restrict__ kf) {
  __shared__ unsigned short at[64][40];    // x tile   [row][k-local], pad-40
  __shared__ unsigned short bt[272][40];   // proj tile[m][k-local]
  const float* x = (blockIdx.y == 0) ? q : k;
  unsigned short* outp = (blockIdx.y == 0) ? qf : kf;
  int tid = threadIdx.x;
  int w = tid >> 6, l = tid & 63;
  int l16 = l & 15, lg = l >> 4;
  int r0 = blockIdx.x * 64;

  f32x4 acc[17] = {};
  for (int kt = 0; kt < 2; ++kt) {
    int k0 = kt * 32;
    __syncthreads();
    #pragma unroll
    for (int p = 0; p < 2; ++p) {
      int idx = tid + p * 256;
      int row = idx >> 3, kq = idx & 7;
      float4 v = *(const float4*)(x + (size_t)(r0 + row) * Dn + k0 + kq * 4);
      *(ushort4*)&at[row][kq * 4] = f4tobf(v);
    }
    for (int idx = tid; idx < 2176; idx += 256) {
      int mq = idx >> 3, kq = idx & 7;
      float4 v = make_float4(0.f, 0.f, 0.f, 0.f);
      if (mq < Mn) v = *(const float4*)(proj + (size_t)mq * Dn + k0 + kq * 4);
      *(ushort4*)&bt[mq][kq * 4] = f4tobf(v);
    }
    __syncthreads();
    bf16x8 a = *(const bf16x8*)((const char*)&at[0][0] + (w*16 + l16) * 80 + lg * 16);
    #pragma unroll
    for (int ct = 0; ct < 17; ++ct) {
      bf16x8 b = *(const bf16x8*)((const char*)&bt[0][0] + (ct*16 + l16) * 80 + lg * 16);
      acc[ct] = __builtin_amdgcn_mfma_f32_16x16x32_bf16(a, b, acc[ct], 0, 0, 0);
    }
  }
  #pragma unroll
  for (int ct = 0; ct < 17; ++ct)
    #pragma unroll
    for (int reg = 0; reg < 4; ++reg) {
      int row = r0 + w*16 + lg*4 + reg;
      int m = ct*16 + l16;
      float val = 0.f;
      if (m < Mn) val = fmaxf(acc[ct][reg] * DNRM, 0.f) + KEPS;
      outp[(size_t)row * MPn + m] = f2u(val);
    }
}

// ================= K2b: in-place exclusive prefix over chunks ==================
__global__ __launch_bounds__(256) void k_kprefix(float* __restrict__ kpre) {
  int bh = blockIdx.x; int tid = threadIdx.x;
  for (int m = tid; m < MPn; m += 256) {
    float v[NCn];
    #pragma unroll
    for (int c = 0; c < NCn; ++c) v[c] = kpre[((size_t)bh * NCn + c) * MPn + m];
    float acc = 0.f;
    #pragma unroll
    for (int c = 0; c < NCn; ++c) {
      kpre[((size_t)bh * NCn + c) * MPn + m] = acc;
      acc += v[c];
    }
  }
}

// ================= K4: MFMA per-chunk S^T_c[e][m] (768 thr, r10-verified) =========
__global__ __launch_bounds__(768) void k_schunk_mfma(
    const unsigned short* __restrict__ kf,
    const float* __restrict__ v3,
    unsigned short* __restrict__ ST,
    float* __restrict__ kpre) {
  __shared__ unsigned short at[192][40];   // v^T tile  [e][j-local] (pitch 80B)
  __shared__ unsigned short bt[272][36];   // kf^T tile [m][j-local] (pitch 72B)
  int blk = blockIdx.x;
  int bh = blk >> 4, c = blk & 15;
  int tid = threadIdx.x;
  int w = tid >> 6, l = tid & 63;
  int l16 = l & 15, lg = l >> 4;
  size_t vbase = ((size_t)bh * Nn + (size_t)c * Cn) * E3n;
  size_t kbase = ((size_t)bh * Nn + (size_t)c * Cn) * MPn;

  f32x4 acc[17] = {};
  float ks = 0.f;
  for (int kt = 0; kt < 4; ++kt) {
    int jt = kt * 32;
    __syncthreads();
    #pragma unroll
    for (int p = 0; p < 2; ++p) {
      int idx = tid + p * 768;           // 1536 = 48 eq x 32 j
      int j = idx & 31, eq = idx >> 5;
      float4 v = *(const float4*)(v3 + vbase + (size_t)(jt + j) * E3n + eq * 4);
      at[eq*4+0][j] = f2u(v.x); at[eq*4+1][j] = f2u(v.y);
      at[eq*4+2][j] = f2u(v.z); at[eq*4+3][j] = f2u(v.w);
    }
    for (int idx = tid; idx < 1088; idx += 768) {
      int j = idx & 31, mq = idx >> 5;
      uint4 v = *(const uint4*)(kf + kbase + (size_t)(jt + j) * MPn + mq * 8);
      unsigned short tmp[8]; __builtin_memcpy(tmp, &v, 16);
      #pragma unroll
      for (int t = 0; t < 8; ++t) bt[mq*8+t][j] = tmp[t];
    }
    __syncthreads();
    bf16x8 a = *(const bf16x8*)((const char*)&at[0][0] + (w*16 + l16) * 80 + lg * 16);
    #pragma unroll
    for (int ct = 0; ct < 17; ++ct) {
      bf16x8 b = *(const bf16x8*)((const char*)&bt[0][0] + (ct*16 + l16) * 72 + lg * 16);
      acc[ct] = __builtin_amdgcn_mfma_f32_16x16x32_bf16(a, b, acc[ct], 0, 0, 0);
    }
    if (tid < MPn) {
      #pragma unroll
      for (int jq = 0; jq < 4; ++jq) {
        uint4 v = *(const uint4*)((const char*)&bt[0][0] + tid * 72 + jq * 16);
        float a8[8]; unpack8(v, a8);
        #pragma unroll
        for (int t = 0; t < 8; ++t) ks += a8[t];
      }
    }
  }
  size_t stbase = (size_t)blk * MPn * E3n;
  #pragma unroll
  for (int ct = 0; ct < 17; ++ct)
    #pragma unroll
    for (int reg = 0; reg < 4; ++reg) {
      int e_loc = w*16 + lg*4 + reg;
      ST[stbase + (size_t)e_loc * MPn + ct*16 + l16] = f2u(acc[ct][reg]);
    }
  if (tid < MPn)
    kpre[((size_t)bh * NCn + c) * MPn + tid] = ks;
}

// ================= K4b: transpose+bf16 weights: ewt[n][e], dwt[t][c] ==============
__global__ __launch_bounds__(256) void k_wt(const float* __restrict__ enc_w,
    const float* __restrict__ dec_w, unsigned short* __restrict__ ewt,
    unsigned short* __restrict__ dwt) {
  int i = blockIdx.x * 256 + threadIdx.x;
  if (i < 128 * 192) {
    int n = i / 192, e = i - n * 192;
    ewt[i] = f2u(enc_w[(size_t)e * DHn + n]);
  } else {
    int j = i - 128 * 192;
    int t = j >> 7, c = j & 127;
    dwt[(size_t)t * DHn + c] = f2u(dec_w[(size_t)c * Tn + t]);
  }
}

// ================= K5: in-place exclusive prefix of S^T over chunks (flat) ==========
__global__ __launch_bounds__(256) void k_sprefix(unsigned short* __restrict__ S) {
  int bh = blockIdx.x / 51, sub = blockIdx.x % 51;
  int idx4 = sub * 256 + threadIdx.x;          // 51*256 == MPn*E3n/4 exactly
  size_t off = (size_t)idx4 * 4;
  ushort4 v[NCn];
  #pragma unroll
  for (int c = 0; c < NCn; ++c)
    v[c] = *(const ushort4*)(S + ((size_t)(bh * NCn + c)) * MPn * E3n + off);
  float a0 = 0.f, a1 = 0.f, a2 = 0.f, a3 = 0.f;
  #pragma unroll
  for (int c = 0; c < NCn; ++c) {
    ushort4 o;
    unsigned short* op = (unsigned short*)&o;
    op[0] = f2u(a0); op[1] = f2u(a1); op[2] = f2u(a2); op[3] = f2u(a3);
    *(ushort4*)(S + ((size_t)(bh * NCn + c)) * MPn * E3n + off) = o;
    a0 += u2f(v[c].x); a1 += u2f(v[c].y); a2 += u2f(v[c].z); a3 += u2f(v[c].w);
  }
}

// ================= K6: FUSED qk + ctx ==================
// Phase A: qk = mask(qf_c @ kf_c^T) -> LDS qkl[128][136]; rowsums + dden in-LDS.
// Phase B: ctx = (qf @ S_pre + qkl @ v) * (1/dden), r10-verified structure.
__global__ __launch_bounds__(768) void k_attn_mfma(
    const unsigned short* __restrict__ qf,
    const unsigned short* __restrict__ kf,
    const float* __restrict__ kpre,
    const unsigned short* __restrict__ ST,
    const float* __restrict__ v3,
    float* __restrict__ ctx) {
  __shared__ unsigned short at[128][40];    // qf tile (both phases)
  __shared__ unsigned short bt[192][40];    // kf (phase A, rows 0-127) / ST / v^T
  __shared__ unsigned short qkl[128][136];  // masked qk, bf16
  __shared__ float kp[MPn];
  __shared__ float rs_lds[128];
  __shared__ float dd[128];                 // 1/dden
  int blk = blockIdx.x;
  int bh = blk >> 4, c = blk & 15;
  int tid = threadIdx.x;
  int w = tid >> 6, l = tid & 63;
  int l16 = l & 15, lg = l >> 4;
  int wr = w & 3, we = w >> 2;
  size_t qbase = ((size_t)bh * Nn + (size_t)c * Cn) * MPn;
  size_t rbase = (size_t)bh * Nn + (size_t)c * Cn;
  for (int m = tid; m < MPn; m += 768) kp[m] = kpre[((size_t)bh * NCn + c) * MPn + m];

  // ---------- phase A: qk ----------
  f32x4 aq[8] = {};
  for (int kt = 0; kt < 9; ++kt) {
    int mt = kt * 32;
    __syncthreads();
    if (tid < 512) {                     // qf tile 128x32
      int r = tid >> 2, kk = (tid & 3) * 8;
      uint4 v = make_uint4(0u,0u,0u,0u);
      if (mt + kk < MPn) v = *(const uint4*)(qf + qbase + (size_t)r * MPn + mt + kk);
      *(uint4*)((char*)&at[0][0] + r * 80 + kk * 2) = v;
    }
    if (tid >= 256) {                    // kf tile 128x32
      int t2 = tid - 256;
      int r = t2 >> 2, kk = (t2 & 3) * 8;
      uint4 v = make_uint4(0u,0u,0u,0u);
      if (mt + kk < MPn) v = *(const uint4*)(kf + qbase + (size_t)r * MPn + mt + kk);
      *(uint4*)((char*)&bt[0][0] + r * 80 + kk * 2) = v;
    }
    __syncthreads();
    if (w < 8) {                         // 8 waves x 16 rows = 128 rows
      bf16x8 a = *(const bf16x8*)((const char*)&at[0][0] + (w*16 + l16) * 80 + lg * 16);
      #pragma unroll
      for (int ct = 0; ct < 8; ++ct) {
        bf16x8 b = *(const bf16x8*)((const char*)&bt[0][0] + (ct*16 + l16) * 80 + lg * 16);
        aq[ct] = __builtin_amdgcn_mfma_f32_16x16x32_bf16(a, b, aq[ct], 0, 0, 0);
      }
    }
  }
  if (w < 8) {                           // mask, store to qkl, rowsums
    float rs[4] = {};
    #pragma unroll
    for (int ct = 0; ct < 8; ++ct)
      #pragma unroll
      for (int reg = 0; reg < 4; ++reg) {
        int row = w*16 + lg*4 + reg;
        int col = ct*16 + l16;
        float v = (col <= row) ? aq[ct][reg] : 0.f;
        qkl[row][col] = f2u(v);
        rs[reg] += v;
      }
    #pragma unroll
    for (int reg = 0; reg < 4; ++reg) {
      float s = rs[reg];
      s += __shfl_xor(s, 1); s += __shfl_xor(s, 2);
      s += __shfl_xor(s, 4); s += __shfl_xor(s, 8);
      if (l16 == 0) rs_lds[w*16 + lg*4 + reg] = s;
    }
  }
  __syncthreads();
  if (tid < 128) {                       // dden (qf rows are L2-warm)
    float dot = 0.f, qs = 0.f;
    const unsigned short* qrow = qf + qbase + (size_t)tid * MPn;
    for (int m = 0; m < MPn; m += 8) {
      uint4 v = *(const uint4*)(qrow + m);
      float a[8]; unpack8(v, a);
      #pragma unroll
      for (int t = 0; t < 8; ++t) { dot += a[t] * kp[m + t]; qs += a[t]; }
    }
    dd[tid] = 1.f / (rs_lds[tid] + dot + DEPS * qs);
  }

  // ---------- phase B: ctx ----------
  f32x4 acc[2][4] = {};
  size_t sbase = (size_t)blk * MPn * E3n;
  for (int kt = 0; kt < 9; ++kt) {       // qf @ S^T
    int mt = kt * 32;
    __syncthreads();
    if (tid < 512) {
      int r = tid >> 2, kk = (tid & 3) * 8;
      uint4 v = make_uint4(0u,0u,0u,0u);
      if (mt + kk < MPn) v = *(const uint4*)(qf + qbase + (size_t)r * MPn + mt + kk);
      *(uint4*)((char*)&at[0][0] + r * 80 + kk * 2) = v;
    }
    {
      int r = tid >> 2, kk = (tid & 3) * 8;
      uint4 v = make_uint4(0u,0u,0u,0u);
      if (mt + kk < MPn) v = *(const uint4*)(ST + sbase + (size_t)r * MPn + mt + kk);
      *(uint4*)((char*)&bt[0][0] + r * 80 + kk * 2) = v;
    }
    __syncthreads();
    bf16x8 a0 = *(const bf16x8*)((const char*)&at[0][0] + (wr*32 + l16) * 80 + lg * 16);
    bf16x8 a1 = *(const bf16x8*)((const char*)&at[0][0] + (wr*32 + 16 + l16) * 80 + lg * 16);
    #pragma unroll
    for (int ct = 0; ct < 4; ++ct) {
      bf16x8 b = *(const bf16x8*)((const char*)&bt[0][0] + (we*64 + ct*16 + l16) * 80 + lg * 16);
      acc[0][ct] = __builtin_amdgcn_mfma_f32_16x16x32_bf16(a0, b, acc[0][ct], 0, 0, 0);
      acc[1][ct] = __builtin_amdgcn_mfma_f32_16x16x32_bf16(a1, b, acc[1][ct], 0, 0, 0);
    }
  }
  size_t vb3 = ((size_t)bh * Nn + (size_t)c * Cn) * E3n;
  for (int kt = 0; kt < 4; ++kt) {       // qkl @ v
    int jt = kt * 32;
    __syncthreads();
    #pragma unroll
    for (int p = 0; p < 2; ++p) {        // v^T tile [192 e][32 j]
      int idx = tid + p * 768;
      int j = idx & 31, eq = idx >> 5;
      float4 v = *(const float4*)(v3 + vb3 + (size_t)(jt + j) * E3n + eq * 4);
      bt[eq*4+0][j] = f2u(v.x); bt[eq*4+1][j] = f2u(v.y);
      bt[eq*4+2][j] = f2u(v.z); bt[eq*4+3][j] = f2u(v.w);
    }
    __syncthreads();
    bf16x8 a0 = *(const bf16x8*)&qkl[wr*32 + l16][jt + lg*8];
    bf16x8 a1 = *(const bf16x8*)&qkl[wr*32 + 16 + l16][jt + lg*8];
    #pragma unroll
    for (int ct = 0; ct < 4; ++ct) {
      bf16x8 b = *(const bf16x8*)((const char*)&bt[0][0] + (we*64 + ct*16 + l16) * 80 + lg * 16);
      acc[0][ct] = __builtin_amdgcn_mfma_f32_16x16x32_bf16(a0, b, acc[0][ct], 0, 0, 0);
      acc[1][ct] = __builtin_amdgcn_mfma_f32_16x16x32_bf16(a1, b, acc[1][ct], 0, 0, 0);
    }
  }
  #pragma unroll
  for (int rt = 0; rt < 2; ++rt)
    #pragma unroll
    for (int ct = 0; ct < 4; ++ct)
      #pragma unroll
      for (int reg = 0; reg < 4; ++reg) {
        int row = wr*32 + rt*16 + lg*4 + reg;
        ctx[(rbase + row) * (size_t)E3n + we*64 + ct*16 + l16] = acc[rt][ct][reg] * dd[row];
      }
}

// ================= K7: fused predictor: MFMA enc -> LN+GELU -> MFMA dec -> softmax ==
__global__ __launch_bounds__(256) void k_pred_fused(
    const float* __restrict__ ctx,
    const unsigned short* __restrict__ ewt,
    const unsigned short* __restrict__ dwt,
    const float* __restrict__ enc_b, const float* __restrict__ ln_g,
    const float* __restrict__ ln_b, const float* __restrict__ dec_b,
    float* __restrict__ probs) {
  __shared__ unsigned short at[128][40];
  __shared__ unsigned short bt[128][40];
  __shared__ unsigned short ht[128][200];
  int tid = threadIdx.x;
  int w = tid >> 6, l = tid & 63;
  int l16 = l & 15, lg = l >> 4;
  size_t r0 = (size_t)blockIdx.x * 128;

  float ebv[8], ggv[8], llv[8], dbv[8];
  #pragma unroll
  for (int ct = 0; ct < 8; ++ct) {
    ebv[ct] = enc_b[ct*16 + l16];
    ggv[ct] = ln_g[ct*16 + l16];
    llv[ct] = ln_b[ct*16 + l16];
    dbv[ct] = dec_b[ct*16 + l16];
  }

  f32x4 acc1[2][8] = {};
  for (int kt = 0; kt < 6; ++kt) {
    int k0 = kt * 32;
    __syncthreads();
    #pragma unroll
    for (int p = 0; p < 4; ++p) {
      int idx = tid + p * 256;
      int row = idx >> 3, kq = idx & 7;
      float4 v = *(const float4*)(ctx + (r0 + row) * E3n + k0 + kq * 4);
      *(ushort4*)&at[row][kq * 4] = f4tobf(v);
    }
    #pragma unroll
    for (int p = 0; p < 2; ++p) {
      int idx = tid + p * 256;
      int n = idx >> 2, kq = idx & 3;
      *(uint4*)&bt[n][kq * 8] = *(const uint4*)(ewt + (size_t)n * E3n + k0 + kq * 8);
    }
    __syncthreads();
    bf16x8 a0 = *(const bf16x8*)((const char*)&at[0][0] + (w*32 + l16) * 80 + lg * 16);
    bf16x8 a1 = *(const bf16x8*)((const char*)&at[0][0] + (w*32 + 16 + l16) * 80 + lg * 16);
    #pragma unroll
    for (int ct = 0; ct < 8; ++ct) {
      bf16x8 b = *(const bf16x8*)((const char*)&bt[0][0] + (ct*16 + l16) * 80 + lg * 16);
      acc1[0][ct] = __builtin_amdgcn_mfma_f32_16x16x32_bf16(a0, b, acc1[0][ct], 0, 0, 0);
      acc1[1][ct] = __builtin_amdgcn_mfma_f32_16x16x32_bf16(a1, b, acc1[1][ct], 0, 0, 0);
    }
  }
  #pragma unroll
  for (int rt = 0; rt < 2; ++rt) {
    #pragma unroll
    for (int reg = 0; reg < 4; ++reg) {
      float hv[8];
      float s = 0.f, s2 = 0.f;
      #pragma unroll
      for (int ct = 0; ct < 8; ++ct) {
        float v = acc1[rt][ct][reg] + ebv[ct];
        hv[ct] = v; s += v; s2 += v * v;
      }
      #pragma unroll
      for (int m = 1; m < 16; m <<= 1) { s += __shfl_xor(s, m); s2 += __shfl_xor(s2, m); }
      float mu = s * (1.f / 128.f);
      float var = s2 * (1.f / 128.f) - mu * mu;
      float rsq = rsqrtf(var + LNEPS);
      int row = w*32 + rt*16 + lg*4 + reg;
      #pragma unroll
      for (int ct = 0; ct < 8; ++ct) {
        float v = (hv[ct] - mu) * rsq * ggv[ct] + llv[ct];
        v = 0.5f * v * (1.f + erff(v * 0.70710678118654752f));
        ht[row][ct*16 + l16] = f2u(v);
      }
    }
  }
  f32x4 acc2[2][8] = {};
  for (int kt = 0; kt < 4; ++kt) {
    int c0 = kt * 32;
    __syncthreads();
    #pragma unroll
    for (int p = 0; p < 2; ++p) {
      int idx = tid + p * 256;
      int t = idx >> 2, kq = idx & 3;
      *(uint4*)&bt[t][kq * 8] = *(const uint4*)(dwt + (size_t)t * DHn + c0 + kq * 8);
    }
    __syncthreads();
    bf16x8 a0 = *(const bf16x8*)&ht[w*32 + l16][c0 + lg*8];
    bf16x8 a1 = *(const bf16x8*)&ht[w*32 + 16 + l16][c0 + lg*8];
    #pragma unroll
    for (int ct = 0; ct < 8; ++ct) {
      bf16x8 b = *(const bf16x8*)((const char*)&bt[0][0] + (ct*16 + l16) * 80 + lg * 16);
      acc2[0][ct] = __builtin_amdgcn_mfma_f32_16x16x32_bf16(a0, b, acc2[0][ct], 0, 0, 0);
      acc2[1][ct] = __builtin_amdgcn_mfma_f32_16x16x32_bf16(a1, b, acc2[1][ct], 0, 0, 0);
    }
  }
  #pragma unroll
  for (int rt = 0; rt < 2; ++rt) {
    #pragma unroll
    for (int reg = 0; reg < 4; ++reg) {
      float sv[8];
      float m = -1e30f;
      #pragma unroll
      for (int ct = 0; ct < 8; ++ct) {
        sv[ct] = acc2[rt][ct][reg] + dbv[ct];
        m = fmaxf(m, sv[ct]);
      }
      #pragma unroll
      for (int mm = 1; mm < 16; mm <<= 1) m = fmaxf(m, __shfl_xor(m, mm));
      float s = 0.f;
      #pragma unroll
      for (int ct = 0; ct < 8; ++ct) { sv[ct] = expf(sv[ct] - m); s += sv[ct]; }
      #pragma unroll
      for (int mm = 1; mm < 16; mm <<= 1) s += __shfl_xor(s, mm);
      float inv = 1.f / s;
      int row = w*32 + rt*16 + lg*4 + reg;
      #pragma unroll
      for (int ct = 0; ct < 8; ++ct)
        probs[(r0 + row) * (size_t)Tn + ct*16 + l16] = sv[ct] * inv;
    }
  }
}

// ================= launch ==================
extern "C" void kernel_launch(void* const* d_in, const int* in_sizes, int n_in,
                              void* d_out, int out_size, void* d_ws, size_t ws_size,
                              hipStream_t stream) {
  const float* q     = (const float*)d_in[0];
  const float* k     = (const float*)d_in[1];
  const float* v3    = (const float*)d_in[2];
  const float* proj  = (const float*)d_in[3];
  const float* enc_w = (const float*)d_in[4];
  const float* enc_b = (const float*)d_in[5];
  const float* ln_g  = (const float*)d_in[6];
  const float* ln_b  = (const float*)d_in[7];
  const float* dec_w = (const float*)d_in[8];
  const float* dec_b = (const float*)d_in[9];
  float* out = (float*)d_out;
  char* ws = (char*)d_ws;
  if (ws_size < WS_NEED) return;

  unsigned short* qf   = (unsigned short*)(ws + OFF_QF);
  unsigned short* kf   = (unsigned short*)(ws + OFF_KF);
  float*          kpre = (float*)(ws + OFF_KPRE);
  unsigned short* ST   = (unsigned short*)(ws + OFF_S);
  unsigned short* ewt  = (unsigned short*)(ws + OFF_WT);           // dead qk region
  unsigned short* dwt  = (unsigned short*)(ws + OFF_WT + 49152);
  float* ctx   = out;
  float* probs = out + (size_t)BHn * Nn * E3n;

  k_features_mfma<<<dim3(BHn * Nn / 64, 2), 256, 0, stream>>>(q, k, proj, qf, kf);
  k_schunk_mfma <<<dim3(BHn * NCn),     768, 0, stream>>>(kf, v3, ST, kpre);
  k_kprefix     <<<dim3(BHn),           256, 0, stream>>>(kpre);
  k_wt          <<<dim3(160),           256, 0, stream>>>(enc_w, dec_w, ewt, dwt);
  k_sprefix     <<<dim3(BHn * 51),      256, 0, stream>>>(ST);
  k_attn_mfma   <<<dim3(BHn * NCn),     768, 0, stream>>>(qf, kf, kpre, ST, v3, ctx);
  k_pred_fused  <<<dim3(BHn * Nn / 128),256, 0, stream>>>(ctx, ewt, dwt, enc_b, ln_g,
                                                          ln_b, dec_b, probs);
}

// Round 13
// 153.803 us; speedup vs baseline: 1.1175x; 1.1175x over previous
//
#include <hip/hip_runtime.h>
#include <hip/hip_bf16.h>
#include <math.h>

// ---------------- problem constants ----------------
constexpr int Bn = 2, Hn = 12, BHn = 24;
constexpr int Nn = 2048, Dn = 64;
constexpr int Mn = 266, MPn = 272;          // M padded to 272 (zero-filled)
constexpr int E3n = 192, DHn = 128, Tn = 128;
constexpr int Cn = 128, NCn = 16;           // chunking

#define DNRM 0.35355339059327373f   // 64^-0.25
#define KEPS 1e-3f
#define DEPS 1e-6f
#define LNEPS 1e-5f

// ---------------- ws layout (bytes) ----------------
static const size_t OFF_QF   = 0;            // bf16 [BH][N][MP]   26,738,688
static const size_t OFF_KF   = 26738688;     // bf16 [BH][N][MP]   (live until k_qk)
static const size_t OFF_QK   = 53477376;     // bf16 [BH][NC][C][C] 12,582,912
static const size_t OFF_D    = 66060288;     // f32  [BH][N]          196,608
static const size_t OFF_KPRE = 66256896;     // f32  [BH][NC][MP]     417,792
static const size_t OFF_S    = 66674688;     // bf16 [BH][NC][192][272] (S^T) 40,108,032
static const size_t OFF_WT   = OFF_KF;       // bf16 ewt+dwt (aliases kf; k_wt runs AFTER k_qk)
static const size_t WS_NEED  = 106782720;

// ---------------- helpers ----------------
using bf16x8 = __attribute__((ext_vector_type(8))) short;
using f32x4  = __attribute__((ext_vector_type(4))) float;

__device__ inline float u2f(unsigned int u) {
  union { float f; unsigned int i; } c; c.i = u << 16; return c.f;
}
__device__ inline unsigned short f2u(float x) {
  __hip_bfloat16 h = __float2bfloat16(x);
  unsigned short u; __builtin_memcpy(&u, &h, 2); return u;
}
__device__ inline void unpack8(uint4 v, float* a) {
  a[0] = u2f(v.x & 0xffffu); a[1] = u2f(v.x >> 16);
  a[2] = u2f(v.y & 0xffffu); a[3] = u2f(v.y >> 16);
  a[4] = u2f(v.z & 0xffffu); a[5] = u2f(v.z >> 16);
  a[6] = u2f(v.w & 0xffffu); a[7] = u2f(v.w >> 16);
}
__device__ inline ushort4 f4tobf(float4 v) {
  ushort4 o;
  o.x = f2u(v.x); o.y = f2u(v.y); o.z = f2u(v.z); o.w = f2u(v.w);
  return o;
}

// ================= K1: MFMA performer features ==================
__global__ __launch_bounds__(256) void k_features_mfma(
    const float* __restrict__ q, const float* __restrict__ k,
    const float* __restrict__ proj,
    unsigned short* __restrict__ qf, unsigned short* __restrict__ kf) {
  __shared__ unsigned short at[64][40];    // x tile   [row][k-local], pad-40
  __shared__ unsigned short bt[272][40];   // proj tile[m][k-local]
  const float* x = (blockIdx.y == 0) ? q : k;
  unsigned short* outp = (blockIdx.y == 0) ? qf : kf;
  int tid = threadIdx.x;
  int w = tid >> 6, l = tid & 63;
  int l16 = l & 15, lg = l >> 4;
  int r0 = blockIdx.x * 64;

  f32x4 acc[17] = {};
  for (int kt = 0; kt < 2; ++kt) {
    int k0 = kt * 32;
    __syncthreads();
    #pragma unroll
    for (int p = 0; p < 2; ++p) {
      int idx = tid + p * 256;
      int row = idx >> 3, kq = idx & 7;
      float4 v = *(const float4*)(x + (size_t)(r0 + row) * Dn + k0 + kq * 4);
      *(ushort4*)&at[row][kq * 4] = f4tobf(v);
    }
    for (int idx = tid; idx < 2176; idx += 256) {
      int mq = idx >> 3, kq = idx & 7;
      float4 v = make_float4(0.f, 0.f, 0.f, 0.f);
      if (mq < Mn) v = *(const float4*)(proj + (size_t)mq * Dn + k0 + kq * 4);
      *(ushort4*)&bt[mq][kq * 4] = f4tobf(v);
    }
    __syncthreads();
    bf16x8 a = *(const bf16x8*)((const char*)&at[0][0] + (w*16 + l16) * 80 + lg * 16);
    #pragma unroll
    for (int ct = 0; ct < 17; ++ct) {
      bf16x8 b = *(const bf16x8*)((const char*)&bt[0][0] + (ct*16 + l16) * 80 + lg * 16);
      acc[ct] = __builtin_amdgcn_mfma_f32_16x16x32_bf16(a, b, acc[ct], 0, 0, 0);
    }
  }
  #pragma unroll
  for (int ct = 0; ct < 17; ++ct)
    #pragma unroll
    for (int reg = 0; reg < 4; ++reg) {
      int row = r0 + w*16 + lg*4 + reg;
      int m = ct*16 + l16;
      float val = 0.f;
      if (m < Mn) val = fmaxf(acc[ct][reg] * DNRM, 0.f) + KEPS;
      outp[(size_t)row * MPn + m] = f2u(val);
    }
}

// ================= K3: MFMA masked qk + denominator (r10-verified) ==================
__global__ __launch_bounds__(256) void k_qk_mfma(
    const unsigned short* __restrict__ qf,
    const unsigned short* __restrict__ kf,
    const float* __restrict__ kpre,
    unsigned short* __restrict__ qkout,
    float* __restrict__ dden) {
  __shared__ unsigned short at[128][40];
  __shared__ unsigned short ktl[128][40];
  __shared__ float kp[MPn];
  __shared__ float rs_lds[128];
  int blk = blockIdx.x;
  int bh = blk >> 4, c = blk & 15;
  int tid = threadIdx.x;
  int w = tid >> 6, l = tid & 63;
  int l16 = l & 15, lg = l >> 4;
  size_t qbase = ((size_t)bh * Nn + (size_t)c * Cn) * MPn;
  size_t rbase = (size_t)bh * Nn + (size_t)c * Cn;
  for (int m = tid; m < MPn; m += 256) kp[m] = kpre[((size_t)bh * NCn + c) * MPn + m];

  f32x4 acc[2][8] = {};
  for (int kt = 0; kt < 9; ++kt) {
    int mt = kt * 32;
    __syncthreads();
    #pragma unroll
    for (int p = 0; p < 2; ++p) {
      int idx = tid * 8 + p * 2048;
      int r = idx >> 5, kk = idx & 31;
      uint4 va = make_uint4(0u,0u,0u,0u), vk = make_uint4(0u,0u,0u,0u);
      if (mt + kk < MPn) {
        va = *(const uint4*)(qf + qbase + (size_t)r * MPn + mt + kk);
        vk = *(const uint4*)(kf + qbase + (size_t)r * MPn + mt + kk);
      }
      *(uint4*)((char*)&at[0][0] + r * 80 + kk * 2) = va;
      *(uint4*)((char*)&ktl[0][0] + r * 80 + kk * 2) = vk;
    }
    __syncthreads();
    bf16x8 a0 = *(const bf16x8*)((const char*)&at[0][0] + (w*32 + l16) * 80 + lg * 16);
    bf16x8 a1 = *(const bf16x8*)((const char*)&at[0][0] + (w*32 + 16 + l16) * 80 + lg * 16);
    #pragma unroll
    for (int ct = 0; ct < 8; ++ct) {
      bf16x8 b = *(const bf16x8*)((const char*)&ktl[0][0] + (ct*16 + l16) * 80 + lg * 16);
      acc[0][ct] = __builtin_amdgcn_mfma_f32_16x16x32_bf16(a0, b, acc[0][ct], 0, 0, 0);
      acc[1][ct] = __builtin_amdgcn_mfma_f32_16x16x32_bf16(a1, b, acc[1][ct], 0, 0, 0);
    }
  }
  size_t qkbase = (size_t)blk * (Cn * Cn);
  float rs[2][4] = {};
  #pragma unroll
  for (int rt = 0; rt < 2; ++rt)
    #pragma unroll
    for (int ct = 0; ct < 8; ++ct)
      #pragma unroll
      for (int reg = 0; reg < 4; ++reg) {
        int row = w*32 + rt*16 + lg*4 + reg;
        int col = ct*16 + l16;
        float v = (col <= row) ? acc[rt][ct][reg] : 0.f;
        qkout[qkbase + (size_t)row * Cn + col] = f2u(v);
        rs[rt][reg] += v;
      }
  #pragma unroll
  for (int rt = 0; rt < 2; ++rt)
    #pragma unroll
    for (int reg = 0; reg < 4; ++reg) {
      float s = rs[rt][reg];
      s += __shfl_xor(s, 1); s += __shfl_xor(s, 2);
      s += __shfl_xor(s, 4); s += __shfl_xor(s, 8);
      rs[rt][reg] = s;
    }
  if (l16 == 0) {
    #pragma unroll
    for (int rt = 0; rt < 2; ++rt)
      #pragma unroll
      for (int reg = 0; reg < 4; ++reg)
        rs_lds[w*32 + rt*16 + lg*4 + reg] = rs[rt][reg];
  }
  __syncthreads();
  if (tid < 128) {
    float dot = 0.f, qs = 0.f;
    const unsigned short* qrow = qf + qbase + (size_t)tid * MPn;
    for (int m = 0; m < MPn; m += 8) {
      uint4 v = *(const uint4*)(qrow + m);
      float a[8]; unpack8(v, a);
      #pragma unroll
      for (int t = 0; t < 8; ++t) { dot += a[t] * kp[m + t]; qs += a[t]; }
    }
    dden[rbase + tid] = rs_lds[tid] + dot + DEPS * qs;
  }
}

// ================= K4: MFMA per-chunk S^T_c[e][m] (768 thr, r10-verified) =========
__global__ __launch_bounds__(768) void k_schunk_mfma(
    const unsigned short* __restrict__ kf,
    const float* __restrict__ v3,
    unsigned short* __restrict__ ST,
    float* __restrict__ kpre) {
  __shared__ unsigned short at[192][40];   // v^T tile  [e][j-local] (pitch 80B)
  __shared__ unsigned short bt[272][36];   // kf^T tile [m][j-local] (pitch 72B)
  int blk = blockIdx.x;
  int bh = blk >> 4, c = blk & 15;
  int tid = threadIdx.x;
  int w = tid >> 6, l = tid & 63;
  int l16 = l & 15, lg = l >> 4;
  size_t vbase = ((size_t)bh * Nn + (size_t)c * Cn) * E3n;
  size_t kbase = ((size_t)bh * Nn + (size_t)c * Cn) * MPn;

  f32x4 acc[17] = {};
  float ks = 0.f;
  for (int kt = 0; kt < 4; ++kt) {
    int jt = kt * 32;
    __syncthreads();
    #pragma unroll
    for (int p = 0; p < 2; ++p) {
      int idx = tid + p * 768;           // 1536 = 48 eq x 32 j
      int j = idx & 31, eq = idx >> 5;
      float4 v = *(const float4*)(v3 + vbase + (size_t)(jt + j) * E3n + eq * 4);
      at[eq*4+0][j] = f2u(v.x); at[eq*4+1][j] = f2u(v.y);
      at[eq*4+2][j] = f2u(v.z); at[eq*4+3][j] = f2u(v.w);
    }
    for (int idx = tid; idx < 1088; idx += 768) {
      int j = idx & 31, mq = idx >> 5;
      uint4 v = *(const uint4*)(kf + kbase + (size_t)(jt + j) * MPn + mq * 8);
      unsigned short tmp[8]; __builtin_memcpy(tmp, &v, 16);
      #pragma unroll
      for (int t = 0; t < 8; ++t) bt[mq*8+t][j] = tmp[t];
    }
    __syncthreads();
    bf16x8 a = *(const bf16x8*)((const char*)&at[0][0] + (w*16 + l16) * 80 + lg * 16);
    #pragma unroll
    for (int ct = 0; ct < 17; ++ct) {
      bf16x8 b = *(const bf16x8*)((const char*)&bt[0][0] + (ct*16 + l16) * 72 + lg * 16);
      acc[ct] = __builtin_amdgcn_mfma_f32_16x16x32_bf16(a, b, acc[ct], 0, 0, 0);
    }
    if (tid < MPn) {
      #pragma unroll
      for (int jq = 0; jq < 4; ++jq) {
        uint4 v = *(const uint4*)((const char*)&bt[0][0] + tid * 72 + jq * 16);
        float a8[8]; unpack8(v, a8);
        #pragma unroll
        for (int t = 0; t < 8; ++t) ks += a8[t];
      }
    }
  }
  size_t stbase = (size_t)blk * MPn * E3n;
  #pragma unroll
  for (int ct = 0; ct < 17; ++ct)
    #pragma unroll
    for (int reg = 0; reg < 4; ++reg) {
      int e_loc = w*16 + lg*4 + reg;
      ST[stbase + (size_t)e_loc * MPn + ct*16 + l16] = f2u(acc[ct][reg]);
    }
  if (tid < MPn)
    kpre[((size_t)bh * NCn + c) * MPn + tid] = ks;
}

// ================= K4b: transpose+bf16 weights (runs AFTER k_qk: kf dead) =========
__global__ __launch_bounds__(256) void k_wt(const float* __restrict__ enc_w,
    const float* __restrict__ dec_w, unsigned short* __restrict__ ewt,
    unsigned short* __restrict__ dwt) {
  int i = blockIdx.x * 256 + threadIdx.x;
  if (i < 128 * 192) {
    int n = i / 192, e = i - n * 192;
    ewt[i] = f2u(enc_w[(size_t)e * DHn + n]);
  } else {
    int j = i - 128 * 192;
    int t = j >> 7, c = j & 127;
    dwt[(size_t)t * DHn + c] = f2u(dec_w[(size_t)c * Tn + t]);
  }
}

// ================= K5: merged sprefix (blocks 0..1223) + kprefix (1224..1247) ======
__global__ __launch_bounds__(256) void k_aux(unsigned short* __restrict__ S,
                                             float* __restrict__ kpre) {
  if (blockIdx.x < BHn * 51) {
    int bh = blockIdx.x / 51, sub = blockIdx.x % 51;
    int idx4 = sub * 256 + threadIdx.x;        // 51*256 == MPn*E3n/4 exactly
    size_t off = (size_t)idx4 * 4;
    ushort4 v[NCn];
    #pragma unroll
    for (int c = 0; c < NCn; ++c)
      v[c] = *(const ushort4*)(S + ((size_t)(bh * NCn + c)) * MPn * E3n + off);
    float a0 = 0.f, a1 = 0.f, a2 = 0.f, a3 = 0.f;
    #pragma unroll
    for (int c = 0; c < NCn; ++c) {
      ushort4 o;
      unsigned short* op = (unsigned short*)&o;
      op[0] = f2u(a0); op[1] = f2u(a1); op[2] = f2u(a2); op[3] = f2u(a3);
      *(ushort4*)(S + ((size_t)(bh * NCn + c)) * MPn * E3n + off) = o;
      a0 += u2f(v[c].x); a1 += u2f(v[c].y); a2 += u2f(v[c].z); a3 += u2f(v[c].w);
    }
  } else {
    int bh = blockIdx.x - BHn * 51;
    int tid = threadIdx.x;
    for (int m = tid; m < MPn; m += 256) {
      float v[NCn];
      #pragma unroll
      for (int c = 0; c < NCn; ++c) v[c] = kpre[((size_t)bh * NCn + c) * MPn + m];
      float acc = 0.f;
      #pragma unroll
      for (int c = 0; c < NCn; ++c) {
        kpre[((size_t)bh * NCn + c) * MPn + m] = acc;
        acc += v[c];
      }
    }
  }
}

// ================= K6: MFMA ctx = (qf@S_pre + qk@v) / d (768 thr, r10-verified) ====
__global__ __launch_bounds__(768) void k_ctx_mfma(
    const unsigned short* __restrict__ qf,
    const unsigned short* __restrict__ qkm,
    const unsigned short* __restrict__ ST,
    const float* __restrict__ v3,
    const float* __restrict__ dden,
    float* __restrict__ ctx) {
  __shared__ unsigned short at[128][40];   // qf / qk tile
  __shared__ unsigned short bt[192][40];   // ST / v^T tile (full e)
  __shared__ float dd[128];
  int blk = blockIdx.x;
  int bh = blk >> 4, c = blk & 15;
  int tid = threadIdx.x;
  int w = tid >> 6, l = tid & 63;
  int l16 = l & 15, lg = l >> 4;
  int wr = w & 3, we = w >> 2;
  size_t qbase = ((size_t)bh * Nn + (size_t)c * Cn) * MPn;
  size_t sbase = (size_t)blk * MPn * E3n;
  size_t rbase = (size_t)bh * Nn + (size_t)c * Cn;
  if (tid < 128) dd[tid] = dden[rbase + tid];

  f32x4 acc[2][4] = {};
  for (int kt = 0; kt < 9; ++kt) {
    int mt = kt * 32;
    __syncthreads();
    if (tid < 512) {           // qf tile 128x32
      int r = tid >> 2, kk = (tid & 3) * 8;
      uint4 v = make_uint4(0u,0u,0u,0u);
      if (mt + kk < MPn) v = *(const uint4*)(qf + qbase + (size_t)r * MPn + mt + kk);
      *(uint4*)((char*)&at[0][0] + r * 80 + kk * 2) = v;
    }
    {                          // ST tile 192x32
      int r = tid >> 2, kk = (tid & 3) * 8;
      uint4 v = make_uint4(0u,0u,0u,0u);
      if (mt + kk < MPn) v = *(const uint4*)(ST + sbase + (size_t)r * MPn + mt + kk);
      *(uint4*)((char*)&bt[0][0] + r * 80 + kk * 2) = v;
    }
    __syncthreads();
    bf16x8 a0 = *(const bf16x8*)((const char*)&at[0][0] + (wr*32 + l16) * 80 + lg * 16);
    bf16x8 a1 = *(const bf16x8*)((const char*)&at[0][0] + (wr*32 + 16 + l16) * 80 + lg * 16);
    #pragma unroll
    for (int ct = 0; ct < 4; ++ct) {
      bf16x8 b = *(const bf16x8*)((const char*)&bt[0][0] + (we*64 + ct*16 + l16) * 80 + lg * 16);
      acc[0][ct] = __builtin_amdgcn_mfma_f32_16x16x32_bf16(a0, b, acc[0][ct], 0, 0, 0);
      acc[1][ct] = __builtin_amdgcn_mfma_f32_16x16x32_bf16(a1, b, acc[1][ct], 0, 0, 0);
    }
  }
  size_t kkbase = (size_t)blk * (Cn * Cn);
  size_t vb3 = ((size_t)bh * Nn + (size_t)c * Cn) * E3n;
  for (int kt = 0; kt < 4; ++kt) {
    int jt = kt * 32;
    __syncthreads();
    if (tid < 512) {           // qk tile 128x32
      int r = tid >> 2, kk = (tid & 3) * 8;
      uint4 v = *(const uint4*)(qkm + kkbase + (size_t)r * Cn + jt + kk);
      *(uint4*)((char*)&at[0][0] + r * 80 + kk * 2) = v;
    }
    #pragma unroll
    for (int p = 0; p < 2; ++p) {        // v^T tile [192 e][32 j]
      int idx = tid + p * 768;
      int j = idx & 31, eq = idx >> 5;
      float4 v = *(const float4*)(v3 + vb3 + (size_t)(jt + j) * E3n + eq * 4);
      bt[eq*4+0][j] = f2u(v.x); bt[eq*4+1][j] = f2u(v.y);
      bt[eq*4+2][j] = f2u(v.z); bt[eq*4+3][j] = f2u(v.w);
    }
    __syncthreads();
    bf16x8 a0 = *(const bf16x8*)((const char*)&at[0][0] + (wr*32 + l16) * 80 + lg * 16);
    bf16x8 a1 = *(const bf16x8*)((const char*)&at[0][0] + (wr*32 + 16 + l16) * 80 + lg * 16);
    #pragma unroll
    for (int ct = 0; ct < 4; ++ct) {
      bf16x8 b = *(const bf16x8*)((const char*)&bt[0][0] + (we*64 + ct*16 + l16) * 80 + lg * 16);
      acc[0][ct] = __builtin_amdgcn_mfma_f32_16x16x32_bf16(a0, b, acc[0][ct], 0, 0, 0);
      acc[1][ct] = __builtin_amdgcn_mfma_f32_16x16x32_bf16(a1, b, acc[1][ct], 0, 0, 0);
    }
  }
  #pragma unroll
  for (int rt = 0; rt < 2; ++rt)
    #pragma unroll
    for (int ct = 0; ct < 4; ++ct)
      #pragma unroll
      for (int reg = 0; reg < 4; ++reg) {
        int row = wr*32 + rt*16 + lg*4 + reg;
        float inv = 1.f / dd[row];
        ctx[(rbase + row) * (size_t)E3n + we*64 + ct*16 + l16] = acc[rt][ct][reg] * inv;
      }
}

// ================= K7: fused predictor (r10-verified) ==================
__global__ __launch_bounds__(256) void k_pred_fused(
    const float* __restrict__ ctx,
    const unsigned short* __restrict__ ewt,
    const unsigned short* __restrict__ dwt,
    const float* __restrict__ enc_b, const float* __restrict__ ln_g,
    const float* __restrict__ ln_b, const float* __restrict__ dec_b,
    float* __restrict__ probs) {
  __shared__ unsigned short at[128][40];
  __shared__ unsigned short bt[128][40];
  __shared__ unsigned short ht[128][200];
  int tid = threadIdx.x;
  int w = tid >> 6, l = tid & 63;
  int l16 = l & 15, lg = l >> 4;
  size_t r0 = (size_t)blockIdx.x * 128;

  float ebv[8], ggv[8], llv[8], dbv[8];
  #pragma unroll
  for (int ct = 0; ct < 8; ++ct) {
    ebv[ct] = enc_b[ct*16 + l16];
    ggv[ct] = ln_g[ct*16 + l16];
    llv[ct] = ln_b[ct*16 + l16];
    dbv[ct] = dec_b[ct*16 + l16];
  }

  f32x4 acc1[2][8] = {};
  for (int kt = 0; kt < 6; ++kt) {
    int k0 = kt * 32;
    __syncthreads();
    #pragma unroll
    for (int p = 0; p < 4; ++p) {
      int idx = tid + p * 256;
      int row = idx >> 3, kq = idx & 7;
      float4 v = *(const float4*)(ctx + (r0 + row) * E3n + k0 + kq * 4);
      *(ushort4*)&at[row][kq * 4] = f4tobf(v);
    }
    #pragma unroll
    for (int p = 0; p < 2; ++p) {
      int idx = tid + p * 256;
      int n = idx >> 2, kq = idx & 3;
      *(uint4*)&bt[n][kq * 8] = *(const uint4*)(ewt + (size_t)n * E3n + k0 + kq * 8);
    }
    __syncthreads();
    bf16x8 a0 = *(const bf16x8*)((const char*)&at[0][0] + (w*32 + l16) * 80 + lg * 16);
    bf16x8 a1 = *(const bf16x8*)((const char*)&at[0][0] + (w*32 + 16 + l16) * 80 + lg * 16);
    #pragma unroll
    for (int ct = 0; ct < 8; ++ct) {
      bf16x8 b = *(const bf16x8*)((const char*)&bt[0][0] + (ct*16 + l16) * 80 + lg * 16);
      acc1[0][ct] = __builtin_amdgcn_mfma_f32_16x16x32_bf16(a0, b, acc1[0][ct], 0, 0, 0);
      acc1[1][ct] = __builtin_amdgcn_mfma_f32_16x16x32_bf16(a1, b, acc1[1][ct], 0, 0, 0);
    }
  }
  #pragma unroll
  for (int rt = 0; rt < 2; ++rt) {
    #pragma unroll
    for (int reg = 0; reg < 4; ++reg) {
      float hv[8];
      float s = 0.f, s2 = 0.f;
      #pragma unroll
      for (int ct = 0; ct < 8; ++ct) {
        float v = acc1[rt][ct][reg] + ebv[ct];
        hv[ct] = v; s += v; s2 += v * v;
      }
      #pragma unroll
      for (int m = 1; m < 16; m <<= 1) { s += __shfl_xor(s, m); s2 += __shfl_xor(s2, m); }
      float mu = s * (1.f / 128.f);
      float var = s2 * (1.f / 128.f) - mu * mu;
      float rsq = rsqrtf(var + LNEPS);
      int row = w*32 + rt*16 + lg*4 + reg;
      #pragma unroll
      for (int ct = 0; ct < 8; ++ct) {
        float v = (hv[ct] - mu) * rsq * ggv[ct] + llv[ct];
        v = 0.5f * v * (1.f + erff(v * 0.70710678118654752f));
        ht[row][ct*16 + l16] = f2u(v);
      }
    }
  }
  f32x4 acc2[2][8] = {};
  for (int kt = 0; kt < 4; ++kt) {
    int c0 = kt * 32;
    __syncthreads();
    #pragma unroll
    for (int p = 0; p < 2; ++p) {
      int idx = tid + p * 256;
      int t = idx >> 2, kq = idx & 3;
      *(uint4*)&bt[t][kq * 8] = *(const uint4*)(dwt + (size_t)t * DHn + c0 + kq * 8);
    }
    __syncthreads();
    bf16x8 a0 = *(const bf16x8*)&ht[w*32 + l16][c0 + lg*8];
    bf16x8 a1 = *(const bf16x8*)&ht[w*32 + 16 + l16][c0 + lg*8];
    #pragma unroll
    for (int ct = 0; ct < 8; ++ct) {
      bf16x8 b = *(const bf16x8*)((const char*)&bt[0][0] + (ct*16 + l16) * 80 + lg * 16);
      acc2[0][ct] = __builtin_amdgcn_mfma_f32_16x16x32_bf16(a0, b, acc2[0][ct], 0, 0, 0);
      acc2[1][ct] = __builtin_amdgcn_mfma_f32_16x16x32_bf16(a1, b, acc2[1][ct], 0, 0, 0);
    }
  }
  #pragma unroll
  for (int rt = 0; rt < 2; ++rt) {
    #pragma unroll
    for (int reg = 0; reg < 4; ++reg) {
      float sv[8];
      float m = -1e30f;
      #pragma unroll
      for (int ct = 0; ct < 8; ++ct) {
        sv[ct] = acc2[rt][ct][reg] + dbv[ct];
        m = fmaxf(m, sv[ct]);
      }
      #pragma unroll
      for (int mm = 1; mm < 16; mm <<= 1) m = fmaxf(m, __shfl_xor(m, mm));
      float s = 0.f;
      #pragma unroll
      for (int ct = 0; ct < 8; ++ct) { sv[ct] = expf(sv[ct] - m); s += sv[ct]; }
      #pragma unroll
      for (int mm = 1; mm < 16; mm <<= 1) s += __shfl_xor(s, mm);
      float inv = 1.f / s;
      int row = w*32 + rt*16 + lg*4 + reg;
      #pragma unroll
      for (int ct = 0; ct < 8; ++ct)
        probs[(r0 + row) * (size_t)Tn + ct*16 + l16] = sv[ct] * inv;
    }
  }
}

// ================= launch ==================
extern "C" void kernel_launch(void* const* d_in, const int* in_sizes, int n_in,
                              void* d_out, int out_size, void* d_ws, size_t ws_size,
                              hipStream_t stream) {
  const float* q     = (const float*)d_in[0];
  const float* k     = (const float*)d_in[1];
  const float* v3    = (const float*)d_in[2];
  const float* proj  = (const float*)d_in[3];
  const float* enc_w = (const float*)d_in[4];
  const float* enc_b = (const float*)d_in[5];
  const float* ln_g  = (const float*)d_in[6];
  const float* ln_b  = (const float*)d_in[7];
  const float* dec_w = (const float*)d_in[8];
  const float* dec_b = (const float*)d_in[9];
  float* out = (float*)d_out;
  char* ws = (char*)d_ws;
  if (ws_size < WS_NEED) return;

  unsigned short* qf   = (unsigned short*)(ws + OFF_QF);
  unsigned short* kf   = (unsigned short*)(ws + OFF_KF);
  unsigned short* qk   = (unsigned short*)(ws + OFF_QK);
  float*          dden = (float*)(ws + OFF_D);
  float*          kpre = (float*)(ws + OFF_KPRE);
  unsigned short* ST   = (unsigned short*)(ws + OFF_S);
  unsigned short* ewt  = (unsigned short*)(ws + OFF_WT);           // aliases kf (dead after k_qk)
  unsigned short* dwt  = (unsigned short*)(ws + OFF_WT + 49152);
  float* ctx   = out;
  float* probs = out + (size_t)BHn * Nn * E3n;

  k_features_mfma<<<dim3(BHn * Nn / 64, 2), 256, 0, stream>>>(q, k, proj, qf, kf);
  k_schunk_mfma <<<dim3(BHn * NCn),       768, 0, stream>>>(kf, v3, ST, kpre);
  k_aux         <<<dim3(BHn * 51 + BHn),  256, 0, stream>>>(ST, kpre);
  k_qk_mfma     <<<dim3(BHn * NCn),       256, 0, stream>>>(qf, kf, kpre, qk, dden);
  k_wt          <<<dim3(160),             256, 0, stream>>>(enc_w, dec_w, ewt, dwt);
  k_ctx_mfma    <<<dim3(BHn * NCn),       768, 0, stream>>>(qf, qk, ST, v3, dden, ctx);
  k_pred_fused  <<<dim3(BHn * Nn / 128),  256, 0, stream>>>(ctx, ewt, dwt, enc_b, ln_g,
                                                            ln_b, dec_b, probs);
}